// Round 1
// baseline (2903.446 us; speedup 1.0000x reference)
//
#include <hip/hip_runtime.h>

#define N_NODES   50000
#define N_EDGES   1600000
#define N_GRAPHS  512
#define LAYERS    3
#define D         128
#define EF        16
#define BN_EPS    1e-5f

// ---------------------------------------------------------------------------
// Edge kernel: for each edge e: m = relu(h[src] + edge_attr[e] @ elW + elb)
// then atomicAdd into aggr[dst]. 256 threads = 2 edges in flight, 16 edges/blk.
// N_EDGES = 100000 * 16 exactly -> no tail guard needed.
// ---------------------------------------------------------------------------
__global__ __launch_bounds__(256) void edge_kernel(
    const float* __restrict__ h,
    const float* __restrict__ edge_attr,
    const float* __restrict__ elW,   // [16][128] (this layer)
    const float* __restrict__ elb,   // [128]
    const int*   __restrict__ src,
    const int*   __restrict__ dst,
    float*       __restrict__ aggr)
{
    __shared__ float Ws[EF * D];   // 8 KB
    __shared__ float bs[D];
    const int tid = threadIdx.x;
    for (int i = tid; i < EF * D; i += 256) Ws[i] = elW[i];
    if (tid < D) bs[tid] = elb[tid];
    __syncthreads();

    const int j   = tid & (D - 1);
    const int sub = tid >> 7;            // 0 or 1
    const int e0  = blockIdx.x * 16;

    #pragma unroll 1
    for (int i = 0; i < 16; i += 2) {
        const int e = e0 + i + sub;
        const float4* ea = (const float4*)(edge_attr + (size_t)e * EF);
        float4 a0 = ea[0], a1 = ea[1], a2 = ea[2], a3 = ea[3];
        float acc = bs[j];
        acc = fmaf(a0.x, Ws[ 0*D + j], acc);
        acc = fmaf(a0.y, Ws[ 1*D + j], acc);
        acc = fmaf(a0.z, Ws[ 2*D + j], acc);
        acc = fmaf(a0.w, Ws[ 3*D + j], acc);
        acc = fmaf(a1.x, Ws[ 4*D + j], acc);
        acc = fmaf(a1.y, Ws[ 5*D + j], acc);
        acc = fmaf(a1.z, Ws[ 6*D + j], acc);
        acc = fmaf(a1.w, Ws[ 7*D + j], acc);
        acc = fmaf(a2.x, Ws[ 8*D + j], acc);
        acc = fmaf(a2.y, Ws[ 9*D + j], acc);
        acc = fmaf(a2.z, Ws[10*D + j], acc);
        acc = fmaf(a2.w, Ws[11*D + j], acc);
        acc = fmaf(a3.x, Ws[12*D + j], acc);
        acc = fmaf(a3.y, Ws[13*D + j], acc);
        acc = fmaf(a3.z, Ws[14*D + j], acc);
        acc = fmaf(a3.w, Ws[15*D + j], acc);
        const int s = src[e];
        const int d = dst[e];
        float m = h[s * D + j] + acc;
        m = fmaxf(m, 0.0f);
        atomicAdd(&aggr[d * D + j], m);
    }
}

// ---------------------------------------------------------------------------
// Node GEMM 1: y = relu(BN((h + aggr) @ W1 + b1))
// 64 nodes x 128 feats per block, 256 threads, 8x4 register tile per thread.
// NOTE: y may alias aggr — all aggr reads for a block's node rows complete
// (followed by __syncthreads) before the epilogue writes y to the same rows.
// ---------------------------------------------------------------------------
__global__ __launch_bounds__(256) void node_mlp1(
    const float* __restrict__ h,
    const float* __restrict__ aggr,
    const float* __restrict__ W1,   // [128][128]
    const float* __restrict__ b1,
    const float* __restrict__ bng,
    const float* __restrict__ bnb,
    const float* __restrict__ bnm,
    const float* __restrict__ bnv,
    float*       __restrict__ y)
{
    __shared__ float Ws[32 * D];    // 16 KB
    __shared__ float zs[64 * 32];   // 8 KB
    const int tid = threadIdx.x;
    const int tx = tid & 31;        // feature group (j = tx + 32u)
    const int ty = tid >> 5;        // node group (8 nodes each)
    const int node0 = blockIdx.x * 64;

    float acc[8][4];
    #pragma unroll
    for (int n = 0; n < 8; ++n)
        #pragma unroll
        for (int u = 0; u < 4; ++u) acc[n][u] = 0.0f;

    for (int kc = 0; kc < D; kc += 32) {
        #pragma unroll
        for (int i = 0; i < 16; ++i) {          // 32*128 = 4096 = 16*256
            int idx = tid + i * 256;
            Ws[idx] = W1[(kc + (idx >> 7)) * D + (idx & 127)];
        }
        #pragma unroll
        for (int i = 0; i < 8; ++i) {           // 64*32 = 2048 = 8*256
            int idx = tid + i * 256;
            int n = idx >> 5, k = idx & 31;
            int node = node0 + n;
            float v = 0.0f;
            if (node < N_NODES) {
                int off = node * D + kc + k;
                v = h[off] + aggr[off];
            }
            zs[idx] = v;
        }
        __syncthreads();
        #pragma unroll
        for (int k = 0; k < 32; ++k) {
            float w0 = Ws[k*D + tx];
            float w1 = Ws[k*D + tx + 32];
            float w2 = Ws[k*D + tx + 64];
            float w3 = Ws[k*D + tx + 96];
            #pragma unroll
            for (int n = 0; n < 8; ++n) {
                float zv = zs[(ty*8 + n)*32 + k];
                acc[n][0] = fmaf(zv, w0, acc[n][0]);
                acc[n][1] = fmaf(zv, w1, acc[n][1]);
                acc[n][2] = fmaf(zv, w2, acc[n][2]);
                acc[n][3] = fmaf(zv, w3, acc[n][3]);
            }
        }
        __syncthreads();
    }

    #pragma unroll
    for (int u = 0; u < 4; ++u) {
        int jj = tx + u * 32;
        float scale = bng[jj] * rsqrtf(bnv[jj] + BN_EPS);
        float shift = bnb[jj] - bnm[jj] * scale;
        float bias  = b1[jj];
        #pragma unroll
        for (int n = 0; n < 8; ++n) {
            int node = node0 + ty * 8 + n;
            if (node < N_NODES) {
                float v = (acc[n][u] + bias) * scale + shift;
                y[node * D + jj] = fmaxf(v, 0.0f);
            }
        }
    }
}

// ---------------------------------------------------------------------------
// Node GEMM 2: h_out = relu(y @ W2 + b2); pool[batch[node]] += h_out (atomic).
// ---------------------------------------------------------------------------
__global__ __launch_bounds__(256) void node_mlp2(
    const float* __restrict__ y,
    const float* __restrict__ W2,
    const float* __restrict__ b2,
    float*       __restrict__ hout,
    const int*   __restrict__ batch,
    float*       __restrict__ pool,   // [N_GRAPHS][3*D]
    int layer_off)
{
    __shared__ float Ws[32 * D];
    __shared__ float zs[64 * 32];
    const int tid = threadIdx.x;
    const int tx = tid & 31;
    const int ty = tid >> 5;
    const int node0 = blockIdx.x * 64;

    float acc[8][4];
    #pragma unroll
    for (int n = 0; n < 8; ++n)
        #pragma unroll
        for (int u = 0; u < 4; ++u) acc[n][u] = 0.0f;

    for (int kc = 0; kc < D; kc += 32) {
        #pragma unroll
        for (int i = 0; i < 16; ++i) {
            int idx = tid + i * 256;
            Ws[idx] = W2[(kc + (idx >> 7)) * D + (idx & 127)];
        }
        #pragma unroll
        for (int i = 0; i < 8; ++i) {
            int idx = tid + i * 256;
            int n = idx >> 5, k = idx & 31;
            int node = node0 + n;
            zs[idx] = (node < N_NODES) ? y[node * D + kc + k] : 0.0f;
        }
        __syncthreads();
        #pragma unroll
        for (int k = 0; k < 32; ++k) {
            float w0 = Ws[k*D + tx];
            float w1 = Ws[k*D + tx + 32];
            float w2 = Ws[k*D + tx + 64];
            float w3 = Ws[k*D + tx + 96];
            #pragma unroll
            for (int n = 0; n < 8; ++n) {
                float zv = zs[(ty*8 + n)*32 + k];
                acc[n][0] = fmaf(zv, w0, acc[n][0]);
                acc[n][1] = fmaf(zv, w1, acc[n][1]);
                acc[n][2] = fmaf(zv, w2, acc[n][2]);
                acc[n][3] = fmaf(zv, w3, acc[n][3]);
            }
        }
        __syncthreads();
    }

    #pragma unroll
    for (int u = 0; u < 4; ++u) {
        int jj = tx + u * 32;
        float bias = b2[jj];
        #pragma unroll
        for (int n = 0; n < 8; ++n) {
            int node = node0 + ty * 8 + n;
            if (node < N_NODES) {
                float v = fmaxf(acc[n][u] + bias, 0.0f);
                hout[node * D + jj] = v;
                atomicAdd(&pool[batch[node] * (LAYERS * D) + layer_off + jj], v);
            }
        }
    }
}

// ---------------------------------------------------------------------------
// Head: per graph g: t = relu(pool[g] @ lin1_W + lin1_b); out[g] = t @ lin2_W + lin2_b
// one block of 384 threads per graph.
// ---------------------------------------------------------------------------
__global__ __launch_bounds__(384) void head_kernel(
    const float* __restrict__ pool,
    const float* __restrict__ lin1W,  // [384][384]
    const float* __restrict__ lin1b,  // [384]
    const float* __restrict__ lin2W,  // [384]
    const float* __restrict__ lin2b,  // [1]
    float*       __restrict__ out)
{
    __shared__ float gs[LAYERS * D];
    __shared__ float red[LAYERS * D];
    const int g   = blockIdx.x;
    const int tid = threadIdx.x;
    gs[tid] = pool[g * (LAYERS * D) + tid];
    __syncthreads();

    float acc = lin1b[tid];
    #pragma unroll 4
    for (int k = 0; k < LAYERS * D; ++k)
        acc = fmaf(gs[k], lin1W[k * (LAYERS * D) + tid], acc);
    acc = fmaxf(acc, 0.0f);
    float p = acc * lin2W[tid];

    red[tid] = p;
    __syncthreads();
    if (tid < 128) red[tid] = red[tid] + red[tid + 128] + red[tid + 256];
    __syncthreads();
    if (tid < 64) {
        float v = red[tid] + red[tid + 64];
        v += __shfl_down(v, 32);
        v += __shfl_down(v, 16);
        v += __shfl_down(v, 8);
        v += __shfl_down(v, 4);
        v += __shfl_down(v, 2);
        v += __shfl_down(v, 1);
        if (tid == 0) out[g] = v + lin2b[0];
    }
}

// ---------------------------------------------------------------------------
extern "C" void kernel_launch(void* const* d_in, const int* in_sizes, int n_in,
                              void* d_out, int out_size, void* d_ws, size_t ws_size,
                              hipStream_t stream)
{
    const float* x         = (const float*)d_in[0];
    const float* edge_attr = (const float*)d_in[1];
    const float* elW       = (const float*)d_in[2];
    const float* elb       = (const float*)d_in[3];
    const float* W1        = (const float*)d_in[4];
    const float* b1        = (const float*)d_in[5];
    const float* bn_g      = (const float*)d_in[6];
    const float* bn_b      = (const float*)d_in[7];
    const float* bn_mean   = (const float*)d_in[8];
    const float* bn_var    = (const float*)d_in[9];
    const float* W2        = (const float*)d_in[10];
    const float* b2        = (const float*)d_in[11];
    const float* lin1W     = (const float*)d_in[12];
    const float* lin1b     = (const float*)d_in[13];
    const float* lin2W     = (const float*)d_in[14];
    const float* lin2b     = (const float*)d_in[15];
    const int*   ei        = (const int*)d_in[16];
    const int*   batch     = (const int*)d_in[17];
    const int*   src = ei;
    const int*   dst = ei + N_EDGES;

    // Workspace layout (floats): aggr (aliased as y) | hA | pool  => ~52 MB
    float* aggr = (float*)d_ws;
    float* hA   = aggr + (size_t)N_NODES * D;
    float* pool = hA   + (size_t)N_NODES * D;

    hipMemsetAsync(pool, 0, (size_t)N_GRAPHS * LAYERS * D * sizeof(float), stream);

    const float* hin = x;
    for (int l = 0; l < LAYERS; ++l) {
        hipMemsetAsync(aggr, 0, (size_t)N_NODES * D * sizeof(float), stream);
        edge_kernel<<<N_EDGES / 16, 256, 0, stream>>>(
            hin, edge_attr, elW + (size_t)l * EF * D, elb + l * D, src, dst, aggr);
        node_mlp1<<<(N_NODES + 63) / 64, 256, 0, stream>>>(
            hin, aggr, W1 + (size_t)l * D * D, b1 + l * D,
            bn_g + l * D, bn_b + l * D, bn_mean + l * D, bn_var + l * D,
            aggr /* y aliases aggr */);
        node_mlp2<<<(N_NODES + 63) / 64, 256, 0, stream>>>(
            aggr /* y */, W2 + (size_t)l * D * D, b2 + l * D,
            hA, batch, pool, l * D);
        hin = hA;  // mlp2 never reads its layer input, so hA can self-overwrite next layer
    }

    head_kernel<<<N_GRAPHS, LAYERS * D, 0, stream>>>(
        pool, lin1W, lin1b, lin2W, lin2b, (float*)d_out);
}

// Round 2
// 1673.678 us; speedup vs baseline: 1.7348x; 1.7348x over previous
//
#include <hip/hip_runtime.h>

#define N_NODES   50000
#define N_EDGES   1600000
#define N_GRAPHS  512
#define LAYERS    3
#define D         128
#define EF        16
#define BN_EPS    1e-5f

// ---------------------------------------------------------------------------
// CSR build step 1: histogram of dst. counts must be zeroed before.
// ---------------------------------------------------------------------------
__global__ __launch_bounds__(256) void hist_kernel(
    const int* __restrict__ dst, int* __restrict__ counts)
{
    int e = blockIdx.x * 256 + threadIdx.x;   // grid is exact (1.6M/256)
    atomicAdd(&counts[dst[e]], 1);
}

// ---------------------------------------------------------------------------
// CSR build step 2: exclusive scan of counts -> offsets[N_NODES+1], cursor copy.
// Single block of 1024 threads; each thread owns a contiguous chunk.
// ---------------------------------------------------------------------------
__global__ __launch_bounds__(1024) void scan_kernel(
    const int* __restrict__ counts, int* __restrict__ offsets,
    int* __restrict__ cursor)
{
    __shared__ int part[1024];
    const int t = threadIdx.x;
    const int CH = (N_NODES + 1023) / 1024;   // 49
    const int lo = t * CH;
    const int hi = (lo + CH < N_NODES) ? lo + CH : N_NODES;
    int s = 0;
    for (int i = lo; i < hi; ++i) s += counts[i];
    part[t] = s;
    __syncthreads();
    // Hillis-Steele inclusive scan over 1024 partials
    for (int off = 1; off < 1024; off <<= 1) {
        int v = (t >= off) ? part[t - off] : 0;
        __syncthreads();
        part[t] += v;
        __syncthreads();
    }
    int run = (t > 0) ? part[t - 1] : 0;      // exclusive prefix of this chunk
    for (int i = lo; i < hi; ++i) {
        offsets[i] = run;
        cursor[i]  = run;
        run += counts[i];
    }
    if (t == 1023) offsets[N_NODES] = run;    // total = N_EDGES
}

// ---------------------------------------------------------------------------
// CSR build step 3: scatter edges into dst-sorted order. Copies src index and
// the 64B edge_attr row so per-layer aggregation reads it sequentially.
// ---------------------------------------------------------------------------
__global__ __launch_bounds__(256) void scatter_kernel(
    const int* __restrict__ src, const int* __restrict__ dst,
    const float* __restrict__ edge_attr,
    int* __restrict__ cursor, int* __restrict__ sorted_src,
    float4* __restrict__ sorted_ea)
{
    int e = blockIdx.x * 256 + threadIdx.x;
    int d = dst[e];
    int pos = atomicAdd(&cursor[d], 1);
    sorted_src[pos] = src[e];
    const float4* ea = (const float4*)(edge_attr + (size_t)e * EF);
    float4 a0 = ea[0], a1 = ea[1], a2 = ea[2], a3 = ea[3];
    float4* o = sorted_ea + (size_t)pos * 4;
    o[0] = a0; o[1] = a1; o[2] = a2; o[3] = a3;
}

// ---------------------------------------------------------------------------
// Per-layer aggregation (gather, no atomics):
//   aggr[n][j] = sum_{e in CSR row n} relu(h[src_e][j] + dot16(ea_e, elW[:,j]) + elb[j])
// One 128-thread block per node; thread j holds elW column j in 16 registers.
// 8 edges staged in LDS per iteration (broadcast-read, conflict-free).
// ---------------------------------------------------------------------------
__global__ __launch_bounds__(128) void aggr_kernel(
    const float* __restrict__ h,
    const float* __restrict__ sorted_ea,
    const int*   __restrict__ sorted_src,
    const int*   __restrict__ offsets,
    const float* __restrict__ elW,   // [16][128] this layer
    const float* __restrict__ elb,   // [128]
    float*       __restrict__ aggr)
{
    const int j = threadIdx.x;       // feature 0..127
    const int n = blockIdx.x;

    float w[16];
    #pragma unroll
    for (int k = 0; k < EF; ++k) w[k] = elW[k * D + j];
    const float bias = elb[j];

    const int beg = offsets[n];
    const int end = offsets[n + 1];

    __shared__ __align__(16) float eas[8][EF];
    __shared__ int srcs[8];
    float acc = 0.0f;

    for (int base = beg; base < end; base += 8) {
        const int cnt = (end - base < 8) ? (end - base) : 8;
        {   // stage 8 edges: 128 floats, one per thread (coalesced)
            int ei = j >> 4, f = j & 15;
            if (ei < cnt) eas[ei][f] = sorted_ea[(size_t)(base + ei) * EF + f];
            if (j < cnt) srcs[j] = sorted_src[base + j];
        }
        __syncthreads();
        #pragma unroll
        for (int i = 0; i < 8; ++i) {
            if (i < cnt) {
                const int s = srcs[i];
                const float hv = h[(size_t)s * D + j];
                float4 e0 = *(const float4*)&eas[i][0];
                float4 e1 = *(const float4*)&eas[i][4];
                float4 e2 = *(const float4*)&eas[i][8];
                float4 e3 = *(const float4*)&eas[i][12];
                float dot = bias;
                dot = fmaf(e0.x, w[ 0], dot);
                dot = fmaf(e0.y, w[ 1], dot);
                dot = fmaf(e0.z, w[ 2], dot);
                dot = fmaf(e0.w, w[ 3], dot);
                dot = fmaf(e1.x, w[ 4], dot);
                dot = fmaf(e1.y, w[ 5], dot);
                dot = fmaf(e1.z, w[ 6], dot);
                dot = fmaf(e1.w, w[ 7], dot);
                dot = fmaf(e2.x, w[ 8], dot);
                dot = fmaf(e2.y, w[ 9], dot);
                dot = fmaf(e2.z, w[10], dot);
                dot = fmaf(e2.w, w[11], dot);
                dot = fmaf(e3.x, w[12], dot);
                dot = fmaf(e3.y, w[13], dot);
                dot = fmaf(e3.z, w[14], dot);
                dot = fmaf(e3.w, w[15], dot);
                acc += fmaxf(hv + dot, 0.0f);
            }
        }
        __syncthreads();
    }
    aggr[(size_t)n * D + j] = acc;
}

// ---------------------------------------------------------------------------
// Node GEMM 1: y = relu(BN((h + aggr) @ W1 + b1))   (y may alias aggr)
// ---------------------------------------------------------------------------
__global__ __launch_bounds__(256) void node_mlp1(
    const float* __restrict__ h,
    const float* __restrict__ aggr,
    const float* __restrict__ W1,   // [128][128]
    const float* __restrict__ b1,
    const float* __restrict__ bng,
    const float* __restrict__ bnb,
    const float* __restrict__ bnm,
    const float* __restrict__ bnv,
    float*       __restrict__ y)
{
    __shared__ float Ws[32 * D];    // 16 KB
    __shared__ float zs[64 * 32];   // 8 KB
    const int tid = threadIdx.x;
    const int tx = tid & 31;
    const int ty = tid >> 5;
    const int node0 = blockIdx.x * 64;

    float acc[8][4];
    #pragma unroll
    for (int n = 0; n < 8; ++n)
        #pragma unroll
        for (int u = 0; u < 4; ++u) acc[n][u] = 0.0f;

    for (int kc = 0; kc < D; kc += 32) {
        #pragma unroll
        for (int i = 0; i < 16; ++i) {
            int idx = tid + i * 256;
            Ws[idx] = W1[(kc + (idx >> 7)) * D + (idx & 127)];
        }
        #pragma unroll
        for (int i = 0; i < 8; ++i) {
            int idx = tid + i * 256;
            int n = idx >> 5, k = idx & 31;
            int node = node0 + n;
            float v = 0.0f;
            if (node < N_NODES) {
                int off = node * D + kc + k;
                v = h[off] + aggr[off];
            }
            zs[idx] = v;
        }
        __syncthreads();
        #pragma unroll
        for (int k = 0; k < 32; ++k) {
            float w0 = Ws[k*D + tx];
            float w1 = Ws[k*D + tx + 32];
            float w2 = Ws[k*D + tx + 64];
            float w3 = Ws[k*D + tx + 96];
            #pragma unroll
            for (int n = 0; n < 8; ++n) {
                float zv = zs[(ty*8 + n)*32 + k];
                acc[n][0] = fmaf(zv, w0, acc[n][0]);
                acc[n][1] = fmaf(zv, w1, acc[n][1]);
                acc[n][2] = fmaf(zv, w2, acc[n][2]);
                acc[n][3] = fmaf(zv, w3, acc[n][3]);
            }
        }
        __syncthreads();
    }

    #pragma unroll
    for (int u = 0; u < 4; ++u) {
        int jj = tx + u * 32;
        float scale = bng[jj] * rsqrtf(bnv[jj] + BN_EPS);
        float shift = bnb[jj] - bnm[jj] * scale;
        float bias  = b1[jj];
        #pragma unroll
        for (int n = 0; n < 8; ++n) {
            int node = node0 + ty * 8 + n;
            if (node < N_NODES) {
                float v = (acc[n][u] + bias) * scale + shift;
                y[node * D + jj] = fmaxf(v, 0.0f);
            }
        }
    }
}

// ---------------------------------------------------------------------------
// Node GEMM 2: h_out = relu(y @ W2 + b2); pool[batch[node]] += h_out (atomic).
// ---------------------------------------------------------------------------
__global__ __launch_bounds__(256) void node_mlp2(
    const float* __restrict__ y,
    const float* __restrict__ W2,
    const float* __restrict__ b2,
    float*       __restrict__ hout,
    const int*   __restrict__ batch,
    float*       __restrict__ pool,   // [N_GRAPHS][3*D]
    int layer_off)
{
    __shared__ float Ws[32 * D];
    __shared__ float zs[64 * 32];
    const int tid = threadIdx.x;
    const int tx = tid & 31;
    const int ty = tid >> 5;
    const int node0 = blockIdx.x * 64;

    float acc[8][4];
    #pragma unroll
    for (int n = 0; n < 8; ++n)
        #pragma unroll
        for (int u = 0; u < 4; ++u) acc[n][u] = 0.0f;

    for (int kc = 0; kc < D; kc += 32) {
        #pragma unroll
        for (int i = 0; i < 16; ++i) {
            int idx = tid + i * 256;
            Ws[idx] = W2[(kc + (idx >> 7)) * D + (idx & 127)];
        }
        #pragma unroll
        for (int i = 0; i < 8; ++i) {
            int idx = tid + i * 256;
            int n = idx >> 5, k = idx & 31;
            int node = node0 + n;
            zs[idx] = (node < N_NODES) ? y[node * D + kc + k] : 0.0f;
        }
        __syncthreads();
        #pragma unroll
        for (int k = 0; k < 32; ++k) {
            float w0 = Ws[k*D + tx];
            float w1 = Ws[k*D + tx + 32];
            float w2 = Ws[k*D + tx + 64];
            float w3 = Ws[k*D + tx + 96];
            #pragma unroll
            for (int n = 0; n < 8; ++n) {
                float zv = zs[(ty*8 + n)*32 + k];
                acc[n][0] = fmaf(zv, w0, acc[n][0]);
                acc[n][1] = fmaf(zv, w1, acc[n][1]);
                acc[n][2] = fmaf(zv, w2, acc[n][2]);
                acc[n][3] = fmaf(zv, w3, acc[n][3]);
            }
        }
        __syncthreads();
    }

    #pragma unroll
    for (int u = 0; u < 4; ++u) {
        int jj = tx + u * 32;
        float bias = b2[jj];
        #pragma unroll
        for (int n = 0; n < 8; ++n) {
            int node = node0 + ty * 8 + n;
            if (node < N_NODES) {
                float v = fmaxf(acc[n][u] + bias, 0.0f);
                hout[node * D + jj] = v;
                atomicAdd(&pool[batch[node] * (LAYERS * D) + layer_off + jj], v);
            }
        }
    }
}

// ---------------------------------------------------------------------------
// Head: per graph g: t = relu(pool[g] @ lin1_W + lin1_b); out[g] = t @ lin2_W + lin2_b
// ---------------------------------------------------------------------------
__global__ __launch_bounds__(384) void head_kernel(
    const float* __restrict__ pool,
    const float* __restrict__ lin1W,  // [384][384]
    const float* __restrict__ lin1b,
    const float* __restrict__ lin2W,
    const float* __restrict__ lin2b,
    float*       __restrict__ out)
{
    __shared__ float gs[LAYERS * D];
    __shared__ float red[LAYERS * D];
    const int g   = blockIdx.x;
    const int tid = threadIdx.x;
    gs[tid] = pool[g * (LAYERS * D) + tid];
    __syncthreads();

    float acc = lin1b[tid];
    #pragma unroll 4
    for (int k = 0; k < LAYERS * D; ++k)
        acc = fmaf(gs[k], lin1W[k * (LAYERS * D) + tid], acc);
    acc = fmaxf(acc, 0.0f);
    float p = acc * lin2W[tid];

    red[tid] = p;
    __syncthreads();
    if (tid < 128) red[tid] = red[tid] + red[tid + 128] + red[tid + 256];
    __syncthreads();
    if (tid < 64) {
        float v = red[tid] + red[tid + 64];
        v += __shfl_down(v, 32);
        v += __shfl_down(v, 16);
        v += __shfl_down(v, 8);
        v += __shfl_down(v, 4);
        v += __shfl_down(v, 2);
        v += __shfl_down(v, 1);
        if (tid == 0) out[g] = v + lin2b[0];
    }
}

// ---------------------------------------------------------------------------
extern "C" void kernel_launch(void* const* d_in, const int* in_sizes, int n_in,
                              void* d_out, int out_size, void* d_ws, size_t ws_size,
                              hipStream_t stream)
{
    const float* x         = (const float*)d_in[0];
    const float* edge_attr = (const float*)d_in[1];
    const float* elW       = (const float*)d_in[2];
    const float* elb       = (const float*)d_in[3];
    const float* W1        = (const float*)d_in[4];
    const float* b1        = (const float*)d_in[5];
    const float* bn_g      = (const float*)d_in[6];
    const float* bn_b      = (const float*)d_in[7];
    const float* bn_mean   = (const float*)d_in[8];
    const float* bn_var    = (const float*)d_in[9];
    const float* W2        = (const float*)d_in[10];
    const float* b2        = (const float*)d_in[11];
    const float* lin1W     = (const float*)d_in[12];
    const float* lin1b     = (const float*)d_in[13];
    const float* lin2W     = (const float*)d_in[14];
    const float* lin2b     = (const float*)d_in[15];
    const int*   ei        = (const int*)d_in[16];
    const int*   batch     = (const int*)d_in[17];
    const int*   src = ei;
    const int*   dst = ei + N_EDGES;

    // Workspace layout (~162 MB):
    //   floats: aggr(y) | hA | pool | sorted_ea
    //   ints:   sorted_src | counts | offsets(+pad) | cursor
    float* aggr      = (float*)d_ws;
    float* hA        = aggr + (size_t)N_NODES * D;              // 6.4M
    float* pool      = hA   + (size_t)N_NODES * D;              // 6.4M
    float* sorted_ea = pool + (size_t)N_GRAPHS * LAYERS * D;    // 196608
    int*   sorted_src = (int*)(sorted_ea + (size_t)N_EDGES * EF);
    int*   counts    = sorted_src + N_EDGES;
    int*   offsets   = counts + N_NODES;
    int*   cursor    = offsets + N_NODES + 4;                   // 50001 padded

    hipMemsetAsync(pool, 0, (size_t)N_GRAPHS * LAYERS * D * sizeof(float), stream);
    hipMemsetAsync(counts, 0, (size_t)N_NODES * sizeof(int), stream);

    // --- CSR build (once per call) ---
    hist_kernel<<<N_EDGES / 256, 256, 0, stream>>>(dst, counts);
    scan_kernel<<<1, 1024, 0, stream>>>(counts, offsets, cursor);
    scatter_kernel<<<N_EDGES / 256, 256, 0, stream>>>(
        src, dst, edge_attr, cursor, sorted_src, (float4*)sorted_ea);

    const float* hin = x;
    for (int l = 0; l < LAYERS; ++l) {
        aggr_kernel<<<N_NODES, 128, 0, stream>>>(
            hin, sorted_ea, sorted_src, offsets,
            elW + (size_t)l * EF * D, elb + l * D, aggr);
        node_mlp1<<<(N_NODES + 63) / 64, 256, 0, stream>>>(
            hin, aggr, W1 + (size_t)l * D * D, b1 + l * D,
            bn_g + l * D, bn_b + l * D, bn_mean + l * D, bn_var + l * D,
            aggr /* y aliases aggr */);
        node_mlp2<<<(N_NODES + 63) / 64, 256, 0, stream>>>(
            aggr /* y */, W2 + (size_t)l * D * D, b2 + l * D,
            hA, batch, pool, l * D);
        hin = hA;
    }

    head_kernel<<<N_GRAPHS, LAYERS * D, 0, stream>>>(
        pool, lin1W, lin1b, lin2W, lin2b, (float*)d_out);
}

// Round 3
// 1461.287 us; speedup vs baseline: 1.9869x; 1.1453x over previous
//
#include <hip/hip_runtime.h>

#define N_NODES   50000
#define N_EDGES   1600000
#define N_GRAPHS  512
#define LAYERS    3
#define D         128
#define EF        16
#define BN_EPS    1e-5f

typedef _Float16 half2v __attribute__((ext_vector_type(2)));

__device__ __forceinline__ float fdot2h(half2v a, half2v b, float c) {
#if __has_builtin(__builtin_amdgcn_fdot2)
    return __builtin_amdgcn_fdot2(a, b, c, false);
#else
    return fmaf((float)a[0], (float)b[0], fmaf((float)a[1], (float)b[1], c));
#endif
}

__device__ __forceinline__ unsigned pack_h2(float x, float y) {
    half2v t; t[0] = (_Float16)x; t[1] = (_Float16)y;
    return __builtin_bit_cast(unsigned, t);
}

// ---------------------------------------------------------------------------
// CSR build step 1: histogram of dst (counts pre-zeroed).
// ---------------------------------------------------------------------------
__global__ __launch_bounds__(256) void hist_kernel(
    const int* __restrict__ dst, int* __restrict__ counts)
{
    int e = blockIdx.x * 256 + threadIdx.x;
    atomicAdd(&counts[dst[e]], 1);
}

// ---------------------------------------------------------------------------
// CSR build step 2: exclusive scan -> offsets[N_NODES+1] + cursor copy.
// ---------------------------------------------------------------------------
__global__ __launch_bounds__(1024) void scan_kernel(
    const int* __restrict__ counts, int* __restrict__ offsets,
    int* __restrict__ cursor)
{
    __shared__ int part[1024];
    const int t = threadIdx.x;
    const int CH = (N_NODES + 1023) / 1024;   // 49
    const int lo = t * CH;
    const int hi = (lo + CH < N_NODES) ? lo + CH : N_NODES;
    int s = 0;
    for (int i = lo; i < hi; ++i) s += counts[i];
    part[t] = s;
    __syncthreads();
    for (int off = 1; off < 1024; off <<= 1) {
        int v = (t >= off) ? part[t - off] : 0;
        __syncthreads();
        part[t] += v;
        __syncthreads();
    }
    int run = (t > 0) ? part[t - 1] : 0;
    for (int i = lo; i < hi; ++i) {
        offsets[i] = run;
        cursor[i]  = run;
        run += counts[i];
    }
    if (t == 1023) offsets[N_NODES] = run;
}

// ---------------------------------------------------------------------------
// CSR build step 3: scatter edges into dst-sorted order; edge_attr -> f16
// (8 half2 = 32B per edge). Halves the random-write traffic vs fp32.
// ---------------------------------------------------------------------------
__global__ __launch_bounds__(256) void scatter_kernel(
    const int* __restrict__ src, const int* __restrict__ dst,
    const float* __restrict__ edge_attr,
    int* __restrict__ cursor, int* __restrict__ sorted_src,
    uint4* __restrict__ sorted_eah)
{
    int e = blockIdx.x * 256 + threadIdx.x;
    int d = dst[e];
    int pos = atomicAdd(&cursor[d], 1);
    sorted_src[pos] = src[e];
    const float4* ea = (const float4*)(edge_attr + (size_t)e * EF);
    float4 a0 = ea[0], a1 = ea[1], a2 = ea[2], a3 = ea[3];
    uint4 o0, o1;
    o0.x = pack_h2(a0.x, a0.y); o0.y = pack_h2(a0.z, a0.w);
    o0.z = pack_h2(a1.x, a1.y); o0.w = pack_h2(a1.z, a1.w);
    o1.x = pack_h2(a2.x, a2.y); o1.y = pack_h2(a2.z, a2.w);
    o1.z = pack_h2(a3.x, a3.y); o1.w = pack_h2(a3.z, a3.w);
    sorted_eah[(size_t)pos * 2]     = o0;
    sorted_eah[(size_t)pos * 2 + 1] = o1;
}

// ---------------------------------------------------------------------------
// Per-layer aggregation (gather, no atomics):
//   zin[n][j] = h[n][j] + sum_{e in row n} relu(h[src_e][j] + dot16(ea_e, elW[:,j]) + elb[j])
// One 128-thread block per node; f16 dot2 for the edge-linear; 16-edge chunks.
// ---------------------------------------------------------------------------
__global__ __launch_bounds__(128) void aggr_kernel(
    const float* __restrict__ h,
    const unsigned* __restrict__ sorted_eah,   // [E][8] half2-packed
    const int*   __restrict__ sorted_src,
    const int*   __restrict__ offsets,
    const float* __restrict__ elW,   // [16][128] this layer
    const float* __restrict__ elb,
    float*       __restrict__ zin)
{
    const int j = threadIdx.x;
    const int n = blockIdx.x;

    half2v w2[8];
    #pragma unroll
    for (int k = 0; k < 8; ++k) {
        half2v t;
        t[0] = (_Float16)elW[(2*k    ) * D + j];
        t[1] = (_Float16)elW[(2*k + 1) * D + j];
        w2[k] = t;
    }
    const float bias = elb[j];

    const int beg = offsets[n];
    const int end = offsets[n + 1];

    __shared__ __align__(16) unsigned eas[16][8];   // 512 B
    __shared__ int srcs[16];
    float acc = 0.0f;

    int base = beg;
    // full 16-edge chunks, no predication in the hot loop
    for (; base + 16 <= end; base += 16) {
        eas[j >> 3][j & 7] = sorted_eah[(size_t)(base + (j >> 3)) * 8 + (j & 7)];
        if (j < 16) srcs[j] = sorted_src[base + j];
        __syncthreads();
        #pragma unroll
        for (int i = 0; i < 16; ++i) {
            const int s = srcs[i];
            const float hv = h[(size_t)s * D + j];
            uint4 p0 = *(const uint4*)&eas[i][0];
            uint4 p1 = *(const uint4*)&eas[i][4];
            float dot = bias;
            dot = fdot2h(__builtin_bit_cast(half2v, p0.x), w2[0], dot);
            dot = fdot2h(__builtin_bit_cast(half2v, p0.y), w2[1], dot);
            dot = fdot2h(__builtin_bit_cast(half2v, p0.z), w2[2], dot);
            dot = fdot2h(__builtin_bit_cast(half2v, p0.w), w2[3], dot);
            dot = fdot2h(__builtin_bit_cast(half2v, p1.x), w2[4], dot);
            dot = fdot2h(__builtin_bit_cast(half2v, p1.y), w2[5], dot);
            dot = fdot2h(__builtin_bit_cast(half2v, p1.z), w2[6], dot);
            dot = fdot2h(__builtin_bit_cast(half2v, p1.w), w2[7], dot);
            acc += fmaxf(hv + dot, 0.0f);
        }
        __syncthreads();
    }
    // tail (< 16 edges)
    const int rem = end - base;
    if (rem > 0) {
        if ((j >> 3) < rem)
            eas[j >> 3][j & 7] = sorted_eah[(size_t)(base + (j >> 3)) * 8 + (j & 7)];
        if (j < rem) srcs[j] = sorted_src[base + j];
        __syncthreads();
        for (int i = 0; i < rem; ++i) {
            const int s = srcs[i];
            const float hv = h[(size_t)s * D + j];
            uint4 p0 = *(const uint4*)&eas[i][0];
            uint4 p1 = *(const uint4*)&eas[i][4];
            float dot = bias;
            dot = fdot2h(__builtin_bit_cast(half2v, p0.x), w2[0], dot);
            dot = fdot2h(__builtin_bit_cast(half2v, p0.y), w2[1], dot);
            dot = fdot2h(__builtin_bit_cast(half2v, p0.z), w2[2], dot);
            dot = fdot2h(__builtin_bit_cast(half2v, p0.w), w2[3], dot);
            dot = fdot2h(__builtin_bit_cast(half2v, p1.x), w2[4], dot);
            dot = fdot2h(__builtin_bit_cast(half2v, p1.y), w2[5], dot);
            dot = fdot2h(__builtin_bit_cast(half2v, p1.z), w2[6], dot);
            dot = fdot2h(__builtin_bit_cast(half2v, p1.w), w2[7], dot);
            acc += fmaxf(hv + dot, 0.0f);
        }
    }
    zin[(size_t)n * D + j] = h[(size_t)n * D + j] + acc;
}

// ---------------------------------------------------------------------------
// Fused node MLP: hout = relu(relu(BN(zin@W1+b1))@W2 + b2); pool += hout.
// z stays in a 32KB LDS tile between the two GEMMs. 64 nodes / 256 thr.
// ---------------------------------------------------------------------------
__global__ __launch_bounds__(256) void node_mlp(
    const float* __restrict__ zin,
    const float* __restrict__ W1, const float* __restrict__ b1,
    const float* __restrict__ bng, const float* __restrict__ bnb,
    const float* __restrict__ bnm, const float* __restrict__ bnv,
    const float* __restrict__ W2, const float* __restrict__ b2,
    float* __restrict__ hout,
    const int* __restrict__ batch,
    float* __restrict__ pool, int layer_off)
{
    __shared__ float Ws[32 * D];     // 16 KB
    __shared__ float zs[64 * 32];    //  8 KB
    __shared__ float zmid[64 * D];   // 32 KB
    const int tid = threadIdx.x;
    const int tx = tid & 31;
    const int ty = tid >> 5;
    const int node0 = blockIdx.x * 64;

    float acc[8][4];
    #pragma unroll
    for (int n = 0; n < 8; ++n)
        #pragma unroll
        for (int u = 0; u < 4; ++u) acc[n][u] = 0.0f;

    // ---- GEMM 1: acc = zin_tile @ W1 ----
    for (int kc = 0; kc < D; kc += 32) {
        #pragma unroll
        for (int i = 0; i < 16; ++i) {
            int idx = tid + i * 256;
            Ws[idx] = W1[(kc + (idx >> 7)) * D + (idx & 127)];
        }
        #pragma unroll
        for (int i = 0; i < 8; ++i) {
            int idx = tid + i * 256;
            int n = idx >> 5, k = idx & 31;
            int node = node0 + n;
            zs[idx] = (node < N_NODES) ? zin[(size_t)node * D + kc + k] : 0.0f;
        }
        __syncthreads();
        #pragma unroll
        for (int k = 0; k < 32; ++k) {
            float w0 = Ws[k*D + tx];
            float w1 = Ws[k*D + tx + 32];
            float w2 = Ws[k*D + tx + 64];
            float w3 = Ws[k*D + tx + 96];
            #pragma unroll
            for (int n = 0; n < 8; ++n) {
                float zv = zs[(ty*8 + n)*32 + k];
                acc[n][0] = fmaf(zv, w0, acc[n][0]);
                acc[n][1] = fmaf(zv, w1, acc[n][1]);
                acc[n][2] = fmaf(zv, w2, acc[n][2]);
                acc[n][3] = fmaf(zv, w3, acc[n][3]);
            }
        }
        __syncthreads();
    }

    // ---- epilogue 1: BN + relu -> zmid (LDS) ----
    #pragma unroll
    for (int u = 0; u < 4; ++u) {
        int jj = tx + u * 32;
        float scale = bng[jj] * rsqrtf(bnv[jj] + BN_EPS);
        float shift = bnb[jj] - bnm[jj] * scale;
        float bias  = b1[jj];
        #pragma unroll
        for (int n = 0; n < 8; ++n) {
            float v = (acc[n][u] + bias) * scale + shift;
            zmid[(ty*8 + n) * D + jj] = fmaxf(v, 0.0f);
        }
    }
    __syncthreads();

    // ---- GEMM 2: acc = zmid @ W2 (zmid from LDS) ----
    #pragma unroll
    for (int n = 0; n < 8; ++n)
        #pragma unroll
        for (int u = 0; u < 4; ++u) acc[n][u] = 0.0f;

    for (int kc = 0; kc < D; kc += 32) {
        #pragma unroll
        for (int i = 0; i < 16; ++i) {
            int idx = tid + i * 256;
            Ws[idx] = W2[(kc + (idx >> 7)) * D + (idx & 127)];
        }
        __syncthreads();
        #pragma unroll
        for (int k = 0; k < 32; ++k) {
            float w0 = Ws[k*D + tx];
            float w1 = Ws[k*D + tx + 32];
            float w2 = Ws[k*D + tx + 64];
            float w3 = Ws[k*D + tx + 96];
            #pragma unroll
            for (int n = 0; n < 8; ++n) {
                float zv = zmid[(ty*8 + n) * D + kc + k];
                acc[n][0] = fmaf(zv, w0, acc[n][0]);
                acc[n][1] = fmaf(zv, w1, acc[n][1]);
                acc[n][2] = fmaf(zv, w2, acc[n][2]);
                acc[n][3] = fmaf(zv, w3, acc[n][3]);
            }
        }
        __syncthreads();
    }

    // ---- epilogue 2: bias + relu -> hout, pool atomics ----
    #pragma unroll
    for (int u = 0; u < 4; ++u) {
        int jj = tx + u * 32;
        float bias = b2[jj];
        #pragma unroll
        for (int n = 0; n < 8; ++n) {
            int node = node0 + ty * 8 + n;
            if (node < N_NODES) {
                float v = fmaxf(acc[n][u] + bias, 0.0f);
                hout[(size_t)node * D + jj] = v;
                atomicAdd(&pool[batch[node] * (LAYERS * D) + layer_off + jj], v);
            }
        }
    }
}

// ---------------------------------------------------------------------------
// Head: out[g] = relu(pool[g] @ lin1_W + lin1_b) @ lin2_W + lin2_b
// ---------------------------------------------------------------------------
__global__ __launch_bounds__(384) void head_kernel(
    const float* __restrict__ pool,
    const float* __restrict__ lin1W,
    const float* __restrict__ lin1b,
    const float* __restrict__ lin2W,
    const float* __restrict__ lin2b,
    float*       __restrict__ out)
{
    __shared__ float gs[LAYERS * D];
    __shared__ float red[LAYERS * D];
    const int g   = blockIdx.x;
    const int tid = threadIdx.x;
    gs[tid] = pool[g * (LAYERS * D) + tid];
    __syncthreads();

    float acc = lin1b[tid];
    #pragma unroll 4
    for (int k = 0; k < LAYERS * D; ++k)
        acc = fmaf(gs[k], lin1W[k * (LAYERS * D) + tid], acc);
    acc = fmaxf(acc, 0.0f);
    float p = acc * lin2W[tid];

    red[tid] = p;
    __syncthreads();
    if (tid < 128) red[tid] = red[tid] + red[tid + 128] + red[tid + 256];
    __syncthreads();
    if (tid < 64) {
        float v = red[tid] + red[tid + 64];
        v += __shfl_down(v, 32);
        v += __shfl_down(v, 16);
        v += __shfl_down(v, 8);
        v += __shfl_down(v, 4);
        v += __shfl_down(v, 2);
        v += __shfl_down(v, 1);
        if (tid == 0) out[g] = v + lin2b[0];
    }
}

// ---------------------------------------------------------------------------
extern "C" void kernel_launch(void* const* d_in, const int* in_sizes, int n_in,
                              void* d_out, int out_size, void* d_ws, size_t ws_size,
                              hipStream_t stream)
{
    const float* x         = (const float*)d_in[0];
    const float* edge_attr = (const float*)d_in[1];
    const float* elW       = (const float*)d_in[2];
    const float* elb       = (const float*)d_in[3];
    const float* W1        = (const float*)d_in[4];
    const float* b1        = (const float*)d_in[5];
    const float* bn_g      = (const float*)d_in[6];
    const float* bn_b      = (const float*)d_in[7];
    const float* bn_mean   = (const float*)d_in[8];
    const float* bn_var    = (const float*)d_in[9];
    const float* W2        = (const float*)d_in[10];
    const float* b2        = (const float*)d_in[11];
    const float* lin1W     = (const float*)d_in[12];
    const float* lin1b     = (const float*)d_in[13];
    const float* lin2W     = (const float*)d_in[14];
    const float* lin2b     = (const float*)d_in[15];
    const int*   ei        = (const int*)d_in[16];
    const int*   batch     = (const int*)d_in[17];
    const int*   src = ei;
    const int*   dst = ei + N_EDGES;

    // Workspace layout (~110 MB):
    float*    zin        = (float*)d_ws;                         // 6.4M f
    float*    hA         = zin  + (size_t)N_NODES * D;           // 6.4M f
    float*    pool       = hA   + (size_t)N_NODES * D;           // 196608 f
    unsigned* sorted_eah = (unsigned*)(pool + (size_t)N_GRAPHS * LAYERS * D); // E*8 u32
    int*      sorted_src = (int*)(sorted_eah + (size_t)N_EDGES * 8);
    int*      counts     = sorted_src + N_EDGES;
    int*      offsets    = counts + N_NODES;
    int*      cursor     = offsets + N_NODES + 4;

    hipMemsetAsync(pool, 0, (size_t)N_GRAPHS * LAYERS * D * sizeof(float), stream);
    hipMemsetAsync(counts, 0, (size_t)N_NODES * sizeof(int), stream);

    // --- CSR build (once per call) ---
    hist_kernel<<<N_EDGES / 256, 256, 0, stream>>>(dst, counts);
    scan_kernel<<<1, 1024, 0, stream>>>(counts, offsets, cursor);
    scatter_kernel<<<N_EDGES / 256, 256, 0, stream>>>(
        src, dst, edge_attr, cursor, sorted_src, (uint4*)sorted_eah);

    const float* hin = x;
    for (int l = 0; l < LAYERS; ++l) {
        aggr_kernel<<<N_NODES, 128, 0, stream>>>(
            hin, sorted_eah, sorted_src, offsets,
            elW + (size_t)l * EF * D, elb + l * D, zin);
        node_mlp<<<(N_NODES + 63) / 64, 256, 0, stream>>>(
            zin, W1 + (size_t)l * D * D, b1 + l * D,
            bn_g + l * D, bn_b + l * D, bn_mean + l * D, bn_var + l * D,
            W2 + (size_t)l * D * D, b2 + l * D,
            hA, batch, pool, l * D);
        hin = hA;
    }

    head_kernel<<<N_GRAPHS, LAYERS * D, 0, stream>>>(
        pool, lin1W, lin1b, lin2W, lin2b, (float*)d_out);
}

// Round 4
// 1251.003 us; speedup vs baseline: 2.3209x; 1.1681x over previous
//
#include <hip/hip_runtime.h>

#define N_NODES   50000
#define N_EDGES   1600000
#define N_GRAPHS  512
#define LAYERS    3
#define D         128
#define EF        16
#define BN_EPS    1e-5f

typedef _Float16 half2v __attribute__((ext_vector_type(2)));
typedef short bf16x8 __attribute__((ext_vector_type(8)));
typedef float f32x4 __attribute__((ext_vector_type(4)));

__device__ __forceinline__ float fdot2h(half2v a, half2v b, float c) {
#if __has_builtin(__builtin_amdgcn_fdot2)
    return __builtin_amdgcn_fdot2(a, b, c, false);
#else
    return fmaf((float)a[0], (float)b[0], fmaf((float)a[1], (float)b[1], c));
#endif
}

__device__ __forceinline__ unsigned pack_h2(float x, float y) {
    half2v t; t[0] = (_Float16)x; t[1] = (_Float16)y;
    return __builtin_bit_cast(unsigned, t);
}

__device__ __forceinline__ unsigned short f2bf(float f) {   // RNE f32->bf16
    unsigned u = __builtin_bit_cast(unsigned, f);
    u += 0x7FFF + ((u >> 16) & 1);
    return (unsigned short)(u >> 16);
}

// ---------------------------------------------------------------------------
// CSR build step 1: histogram of dst (counts pre-zeroed).
// ---------------------------------------------------------------------------
__global__ __launch_bounds__(256) void hist_kernel(
    const int* __restrict__ dst, int* __restrict__ counts)
{
    int e = blockIdx.x * 256 + threadIdx.x;
    atomicAdd(&counts[dst[e]], 1);
}

// ---------------------------------------------------------------------------
// CSR build step 2: exclusive scan -> offsets[N_NODES+1] + cursor copy.
// ---------------------------------------------------------------------------
__global__ __launch_bounds__(1024) void scan_kernel(
    const int* __restrict__ counts, int* __restrict__ offsets,
    int* __restrict__ cursor)
{
    __shared__ int part[1024];
    const int t = threadIdx.x;
    const int CH = (N_NODES + 1023) / 1024;   // 49
    const int lo = t * CH;
    const int hi = (lo + CH < N_NODES) ? lo + CH : N_NODES;
    int s = 0;
    for (int i = lo; i < hi; ++i) s += counts[i];
    part[t] = s;
    __syncthreads();
    for (int off = 1; off < 1024; off <<= 1) {
        int v = (t >= off) ? part[t - off] : 0;
        __syncthreads();
        part[t] += v;
        __syncthreads();
    }
    int run = (t > 0) ? part[t - 1] : 0;
    for (int i = lo; i < hi; ++i) {
        offsets[i] = run;
        cursor[i]  = run;
        run += counts[i];
    }
    if (t == 1023) offsets[N_NODES] = run;
}

// ---------------------------------------------------------------------------
// CSR build step 3: scatter edges into dst-sorted order; edge_attr -> f16.
// ---------------------------------------------------------------------------
__global__ __launch_bounds__(256) void scatter_kernel(
    const int* __restrict__ src, const int* __restrict__ dst,
    const float* __restrict__ edge_attr,
    int* __restrict__ cursor, int* __restrict__ sorted_src,
    uint4* __restrict__ sorted_eah)
{
    int e = blockIdx.x * 256 + threadIdx.x;
    int d = dst[e];
    int pos = atomicAdd(&cursor[d], 1);
    sorted_src[pos] = src[e];
    const float4* ea = (const float4*)(edge_attr + (size_t)e * EF);
    float4 a0 = ea[0], a1 = ea[1], a2 = ea[2], a3 = ea[3];
    uint4 o0, o1;
    o0.x = pack_h2(a0.x, a0.y); o0.y = pack_h2(a0.z, a0.w);
    o0.z = pack_h2(a1.x, a1.y); o0.w = pack_h2(a1.z, a1.w);
    o1.x = pack_h2(a2.x, a2.y); o1.y = pack_h2(a2.z, a2.w);
    o1.z = pack_h2(a3.x, a3.y); o1.w = pack_h2(a3.z, a3.w);
    sorted_eah[(size_t)pos * 2]     = o0;
    sorted_eah[(size_t)pos * 2 + 1] = o1;
}

// ---------------------------------------------------------------------------
// Weight prep: transpose W1/W2 (all layers) to bf16 Wt[out][k], once per call.
// ---------------------------------------------------------------------------
__global__ __launch_bounds__(256) void wprep_kernel(
    const float* __restrict__ W1, const float* __restrict__ W2,
    unsigned short* __restrict__ Wt)
{
    const int matid = blockIdx.x;          // l*2 + (0:W1, 1:W2)
    const int l = matid >> 1;
    const float* srcm = (matid & 1) ? (W2 + (size_t)l * D * D)
                                    : (W1 + (size_t)l * D * D);
    unsigned short* out = Wt + (size_t)matid * D * D;
    for (int i = 0; i < 64; ++i) {
        int idx = threadIdx.x + i * 256;
        int k = idx >> 7, n = idx & 127;
        out[n * D + k] = f2bf(srcm[idx]);
    }
}

// ---------------------------------------------------------------------------
// Per-layer aggregation (gather, no atomics):
//   zin_b[n][j] = bf16( h[n][j] + sum_e relu(h[src_e][j] + dot16(ea_e, elW[:,j]) + elb[j]) )
// ---------------------------------------------------------------------------
__global__ __launch_bounds__(128) void aggr_kernel(
    const float* __restrict__ h,
    const unsigned* __restrict__ sorted_eah,   // [E][8] half2-packed
    const int*   __restrict__ sorted_src,
    const int*   __restrict__ offsets,
    const float* __restrict__ elW,   // [16][128] this layer
    const float* __restrict__ elb,
    unsigned short* __restrict__ zin_b)
{
    const int j = threadIdx.x;
    const int n = blockIdx.x;

    half2v w2[8];
    #pragma unroll
    for (int k = 0; k < 8; ++k) {
        half2v t;
        t[0] = (_Float16)elW[(2*k    ) * D + j];
        t[1] = (_Float16)elW[(2*k + 1) * D + j];
        w2[k] = t;
    }
    const float bias = elb[j];

    const int beg = offsets[n];
    const int end = offsets[n + 1];

    __shared__ __align__(16) unsigned eas[16][8];
    __shared__ int srcs[16];
    float acc = 0.0f;

    int base = beg;
    for (; base + 16 <= end; base += 16) {
        eas[j >> 3][j & 7] = sorted_eah[(size_t)(base + (j >> 3)) * 8 + (j & 7)];
        if (j < 16) srcs[j] = sorted_src[base + j];
        __syncthreads();
        #pragma unroll
        for (int i = 0; i < 16; ++i) {
            const int s = srcs[i];
            const float hv = h[(size_t)s * D + j];
            uint4 p0 = *(const uint4*)&eas[i][0];
            uint4 p1 = *(const uint4*)&eas[i][4];
            float dot = bias;
            dot = fdot2h(__builtin_bit_cast(half2v, p0.x), w2[0], dot);
            dot = fdot2h(__builtin_bit_cast(half2v, p0.y), w2[1], dot);
            dot = fdot2h(__builtin_bit_cast(half2v, p0.z), w2[2], dot);
            dot = fdot2h(__builtin_bit_cast(half2v, p0.w), w2[3], dot);
            dot = fdot2h(__builtin_bit_cast(half2v, p1.x), w2[4], dot);
            dot = fdot2h(__builtin_bit_cast(half2v, p1.y), w2[5], dot);
            dot = fdot2h(__builtin_bit_cast(half2v, p1.z), w2[6], dot);
            dot = fdot2h(__builtin_bit_cast(half2v, p1.w), w2[7], dot);
            acc += fmaxf(hv + dot, 0.0f);
        }
        __syncthreads();
    }
    const int rem = end - base;
    if (rem > 0) {
        if ((j >> 3) < rem)
            eas[j >> 3][j & 7] = sorted_eah[(size_t)(base + (j >> 3)) * 8 + (j & 7)];
        if (j < rem) srcs[j] = sorted_src[base + j];
        __syncthreads();
        for (int i = 0; i < rem; ++i) {
            const int s = srcs[i];
            const float hv = h[(size_t)s * D + j];
            uint4 p0 = *(const uint4*)&eas[i][0];
            uint4 p1 = *(const uint4*)&eas[i][4];
            float dot = bias;
            dot = fdot2h(__builtin_bit_cast(half2v, p0.x), w2[0], dot);
            dot = fdot2h(__builtin_bit_cast(half2v, p0.y), w2[1], dot);
            dot = fdot2h(__builtin_bit_cast(half2v, p0.z), w2[2], dot);
            dot = fdot2h(__builtin_bit_cast(half2v, p0.w), w2[3], dot);
            dot = fdot2h(__builtin_bit_cast(half2v, p1.x), w2[4], dot);
            dot = fdot2h(__builtin_bit_cast(half2v, p1.y), w2[5], dot);
            dot = fdot2h(__builtin_bit_cast(half2v, p1.z), w2[6], dot);
            dot = fdot2h(__builtin_bit_cast(half2v, p1.w), w2[7], dot);
            acc += fmaxf(hv + dot, 0.0f);
        }
    }
    zin_b[(size_t)n * D + j] = f2bf(h[(size_t)n * D + j] + acc);
}

// ---------------------------------------------------------------------------
// Fused node MLP via MFMA (bf16 in, fp32 accumulate):
//   hout = relu(relu(BN(zin@W1+b1))@W2 + b2); pool[batch[n]] += hout.
// Block = 128 nodes, 4 waves; wave = 32 rows x 128 cols (2x8 mfma tiles x K4).
// Layouts (verified m89/m120): A[m=lane&15][k=quad*8+j]; B[k][n=lane&15];
// C/D row=quad*4+reg, col=lane&15.
// ---------------------------------------------------------------------------
__global__ __launch_bounds__(256) void node_mlp(
    const unsigned short* __restrict__ zin_b,   // [N][128] bf16
    const unsigned short* __restrict__ W1t,     // [128 out][128 k] bf16
    const float* __restrict__ b1,
    const float* __restrict__ bng, const float* __restrict__ bnb,
    const float* __restrict__ bnm, const float* __restrict__ bnv,
    const unsigned short* __restrict__ W2t,
    const float* __restrict__ b2,
    float* __restrict__ hout,
    const int* __restrict__ batch,
    float* __restrict__ pool, int layer_off)
{
    __shared__ unsigned short Wb[128 * 136];    // 34.8 KB (B-matrix, +8 pad)
    __shared__ unsigned short zmid[128 * 136];  // 34.8 KB
    __shared__ float scale_s[128], shift_s[128], b2_s[128];

    const int tid  = threadIdx.x;
    const int wv   = tid >> 6;
    const int lane = tid & 63;
    const int q    = lane >> 4;
    const int m    = lane & 15;
    const int node0 = blockIdx.x * 128;

    if (tid < 128) {
        float sc = bng[tid] * rsqrtf(bnv[tid] + BN_EPS);
        scale_s[tid] = sc;
        shift_s[tid] = b1[tid] * sc + bnb[tid] - bnm[tid] * sc;  // BN(b1 fold)
        b2_s[tid]    = b2[tid];
    }

    // stage W1t -> Wb (32 KB, 16B chunks; row pad 136 shorts keeps 16B align)
    #pragma unroll
    for (int i = 0; i < 8; ++i) {
        int c = tid + i * 256;
        *(uint4*)&Wb[(c >> 4) * 136 + (c & 15) * 8] = ((const uint4*)W1t)[c];
    }

    // A fragments straight from global bf16 zin
    bf16x8 a[2][4];
    #pragma unroll
    for (int sub = 0; sub < 2; ++sub) {
        int node = node0 + wv * 32 + sub * 16 + m;
        if (node >= N_NODES) node = N_NODES - 1;
        const uint4* zrow = (const uint4*)(zin_b + (size_t)node * D);
        #pragma unroll
        for (int k = 0; k < 4; ++k)
            a[sub][k] = __builtin_bit_cast(bf16x8, zrow[k * 4 + q]);
    }

    f32x4 acc[2][8];
    #pragma unroll
    for (int s2 = 0; s2 < 2; ++s2)
        #pragma unroll
        for (int t = 0; t < 8; ++t)
            acc[s2][t] = (f32x4){0.f, 0.f, 0.f, 0.f};

    __syncthreads();

    // GEMM 1
    #pragma unroll
    for (int t = 0; t < 8; ++t) {
        const unsigned short* wrow = &Wb[(t * 16 + m) * 136];
        bf16x8 bfr[4];
        #pragma unroll
        for (int k = 0; k < 4; ++k)
            bfr[k] = __builtin_bit_cast(bf16x8, *(const uint4*)&wrow[k * 32 + q * 8]);
        #pragma unroll
        for (int sub = 0; sub < 2; ++sub) {
            acc[sub][t] = __builtin_amdgcn_mfma_f32_16x16x32_bf16(a[sub][0], bfr[0], acc[sub][t], 0, 0, 0);
            acc[sub][t] = __builtin_amdgcn_mfma_f32_16x16x32_bf16(a[sub][1], bfr[1], acc[sub][t], 0, 0, 0);
            acc[sub][t] = __builtin_amdgcn_mfma_f32_16x16x32_bf16(a[sub][2], bfr[2], acc[sub][t], 0, 0, 0);
            acc[sub][t] = __builtin_amdgcn_mfma_f32_16x16x32_bf16(a[sub][3], bfr[3], acc[sub][t], 0, 0, 0);
        }
    }

    // epilogue 1: BN + relu -> zmid (bf16, C/D layout -> LDS)
    #pragma unroll
    for (int sub = 0; sub < 2; ++sub)
        #pragma unroll
        for (int t = 0; t < 8; ++t) {
            int col = t * 16 + m;
            float sc = scale_s[col], sh = shift_s[col];
            #pragma unroll
            for (int rr = 0; rr < 4; ++rr) {
                float v = fmaxf(acc[sub][t][rr] * sc + sh, 0.f);
                int row = wv * 32 + sub * 16 + q * 4 + rr;
                zmid[row * 136 + col] = f2bf(v);
            }
        }

    __syncthreads();   // GEMM1 reads done, zmid complete

    // stage W2t (overwrite Wb); read A2 frags from zmid (stable)
    #pragma unroll
    for (int i = 0; i < 8; ++i) {
        int c = tid + i * 256;
        *(uint4*)&Wb[(c >> 4) * 136 + (c & 15) * 8] = ((const uint4*)W2t)[c];
    }
    bf16x8 a2[2][4];
    #pragma unroll
    for (int sub = 0; sub < 2; ++sub) {
        const unsigned short* zr = &zmid[(wv * 32 + sub * 16 + m) * 136];
        #pragma unroll
        for (int k = 0; k < 4; ++k)
            a2[sub][k] = __builtin_bit_cast(bf16x8, *(const uint4*)&zr[k * 32 + q * 8]);
    }

    #pragma unroll
    for (int s2 = 0; s2 < 2; ++s2)
        #pragma unroll
        for (int t = 0; t < 8; ++t)
            acc[s2][t] = (f32x4){0.f, 0.f, 0.f, 0.f};

    __syncthreads();

    // GEMM 2
    #pragma unroll
    for (int t = 0; t < 8; ++t) {
        const unsigned short* wrow = &Wb[(t * 16 + m) * 136];
        bf16x8 bfr[4];
        #pragma unroll
        for (int k = 0; k < 4; ++k)
            bfr[k] = __builtin_bit_cast(bf16x8, *(const uint4*)&wrow[k * 32 + q * 8]);
        #pragma unroll
        for (int sub = 0; sub < 2; ++sub) {
            acc[sub][t] = __builtin_amdgcn_mfma_f32_16x16x32_bf16(a2[sub][0], bfr[0], acc[sub][t], 0, 0, 0);
            acc[sub][t] = __builtin_amdgcn_mfma_f32_16x16x32_bf16(a2[sub][1], bfr[1], acc[sub][t], 0, 0, 0);
            acc[sub][t] = __builtin_amdgcn_mfma_f32_16x16x32_bf16(a2[sub][2], bfr[2], acc[sub][t], 0, 0, 0);
            acc[sub][t] = __builtin_amdgcn_mfma_f32_16x16x32_bf16(a2[sub][3], bfr[3], acc[sub][t], 0, 0, 0);
        }
    }

    // epilogue 2: bias + relu -> hout (fp32) + pool atomics
    int   pbase[2][4];
    bool  valid[2][4];
    #pragma unroll
    for (int sub = 0; sub < 2; ++sub)
        #pragma unroll
        for (int rr = 0; rr < 4; ++rr) {
            int node = node0 + wv * 32 + sub * 16 + q * 4 + rr;
            valid[sub][rr] = (node < N_NODES);
            pbase[sub][rr] = valid[sub][rr] ? batch[node] * (LAYERS * D) + layer_off : 0;
        }
    #pragma unroll
    for (int sub = 0; sub < 2; ++sub)
        #pragma unroll
        for (int t = 0; t < 8; ++t) {
            int col = t * 16 + m;
            float bias = b2_s[col];
            #pragma unroll
            for (int rr = 0; rr < 4; ++rr) {
                if (valid[sub][rr]) {
                    int node = node0 + wv * 32 + sub * 16 + q * 4 + rr;
                    float v = fmaxf(acc[sub][t][rr] + bias, 0.f);
                    hout[(size_t)node * D + col] = v;
                    atomicAdd(&pool[pbase[sub][rr] + col], v);
                }
            }
        }
}

// ---------------------------------------------------------------------------
// Head: out[g] = relu(pool[g] @ lin1_W + lin1_b) @ lin2_W + lin2_b
// ---------------------------------------------------------------------------
__global__ __launch_bounds__(384) void head_kernel(
    const float* __restrict__ pool,
    const float* __restrict__ lin1W,
    const float* __restrict__ lin1b,
    const float* __restrict__ lin2W,
    const float* __restrict__ lin2b,
    float*       __restrict__ out)
{
    __shared__ float gs[LAYERS * D];
    __shared__ float red[LAYERS * D];
    const int g   = blockIdx.x;
    const int tid = threadIdx.x;
    gs[tid] = pool[g * (LAYERS * D) + tid];
    __syncthreads();

    float acc = lin1b[tid];
    #pragma unroll 4
    for (int k = 0; k < LAYERS * D; ++k)
        acc = fmaf(gs[k], lin1W[k * (LAYERS * D) + tid], acc);
    acc = fmaxf(acc, 0.0f);
    float p = acc * lin2W[tid];

    red[tid] = p;
    __syncthreads();
    if (tid < 128) red[tid] = red[tid] + red[tid + 128] + red[tid + 256];
    __syncthreads();
    if (tid < 64) {
        float v = red[tid] + red[tid + 64];
        v += __shfl_down(v, 32);
        v += __shfl_down(v, 16);
        v += __shfl_down(v, 8);
        v += __shfl_down(v, 4);
        v += __shfl_down(v, 2);
        v += __shfl_down(v, 1);
        if (tid == 0) out[g] = v + lin2b[0];
    }
}

// ---------------------------------------------------------------------------
extern "C" void kernel_launch(void* const* d_in, const int* in_sizes, int n_in,
                              void* d_out, int out_size, void* d_ws, size_t ws_size,
                              hipStream_t stream)
{
    const float* x         = (const float*)d_in[0];
    const float* edge_attr = (const float*)d_in[1];
    const float* elW       = (const float*)d_in[2];
    const float* elb       = (const float*)d_in[3];
    const float* W1        = (const float*)d_in[4];
    const float* b1        = (const float*)d_in[5];
    const float* bn_g      = (const float*)d_in[6];
    const float* bn_b      = (const float*)d_in[7];
    const float* bn_mean   = (const float*)d_in[8];
    const float* bn_var    = (const float*)d_in[9];
    const float* W2        = (const float*)d_in[10];
    const float* b2        = (const float*)d_in[11];
    const float* lin1W     = (const float*)d_in[12];
    const float* lin1b     = (const float*)d_in[13];
    const float* lin2W     = (const float*)d_in[14];
    const float* lin2b     = (const float*)d_in[15];
    const int*   ei        = (const int*)d_in[16];
    const int*   batch     = (const int*)d_in[17];
    const int*   src = ei;
    const int*   dst = ei + N_EDGES;

    // Workspace layout (~98 MB), all 16B-aligned:
    float*          hA         = (float*)d_ws;                              // N*128 f32
    float*          pool       = hA + (size_t)N_NODES * D;                  // G*384 f32
    unsigned short* zin_b      = (unsigned short*)(pool + (size_t)N_GRAPHS * LAYERS * D);
    unsigned short* Wt         = zin_b + (size_t)N_NODES * D;               // 6*16384 bf16
    unsigned*       sorted_eah = (unsigned*)(Wt + 6 * D * D);               // E*8 u32
    int*            sorted_src = (int*)(sorted_eah + (size_t)N_EDGES * 8);
    int*            counts     = sorted_src + N_EDGES;
    int*            offsets    = counts + N_NODES;
    int*            cursor     = offsets + N_NODES + 4;

    hipMemsetAsync(pool, 0, (size_t)N_GRAPHS * LAYERS * D * sizeof(float), stream);
    hipMemsetAsync(counts, 0, (size_t)N_NODES * sizeof(int), stream);

    // --- once-per-call prep ---
    wprep_kernel<<<6, 256, 0, stream>>>(W1, W2, Wt);
    hist_kernel<<<N_EDGES / 256, 256, 0, stream>>>(dst, counts);
    scan_kernel<<<1, 1024, 0, stream>>>(counts, offsets, cursor);
    scatter_kernel<<<N_EDGES / 256, 256, 0, stream>>>(
        src, dst, edge_attr, cursor, sorted_src, (uint4*)sorted_eah);

    const float* hin = x;
    for (int l = 0; l < LAYERS; ++l) {
        aggr_kernel<<<N_NODES, 128, 0, stream>>>(
            hin, sorted_eah, sorted_src, offsets,
            elW + (size_t)l * EF * D, elb + l * D, zin_b);
        node_mlp<<<(N_NODES + 127) / 128, 256, 0, stream>>>(
            zin_b,
            Wt + (size_t)(l * 2)     * D * D, b1 + l * D,
            bn_g + l * D, bn_b + l * D, bn_mean + l * D, bn_var + l * D,
            Wt + (size_t)(l * 2 + 1) * D * D, b2 + l * D,
            hA, batch, pool, l * D);
        hin = hA;
    }

    head_kernel<<<N_GRAPHS, LAYERS * D, 0, stream>>>(
        pool, lin1W, lin1b, lin2W, lin2b, (float*)d_out);
}

// Round 5
// 1016.675 us; speedup vs baseline: 2.8558x; 1.2305x over previous
//
#include <hip/hip_runtime.h>

#define N_NODES   50000
#define N_EDGES   1600000
#define N_GRAPHS  512
#define LAYERS    3
#define D         128
#define EF        16
#define BN_EPS    1e-5f

typedef _Float16 half2v __attribute__((ext_vector_type(2)));
typedef short bf16x8 __attribute__((ext_vector_type(8)));
typedef float f32x4 __attribute__((ext_vector_type(4)));

__device__ __forceinline__ float fdot2h(half2v a, half2v b, float c) {
#if __has_builtin(__builtin_amdgcn_fdot2)
    return __builtin_amdgcn_fdot2(a, b, c, false);
#else
    return fmaf((float)a[0], (float)b[0], fmaf((float)a[1], (float)b[1], c));
#endif
}

__device__ __forceinline__ unsigned pack_h2(float x, float y) {
    half2v t; t[0] = (_Float16)x; t[1] = (_Float16)y;
    return __builtin_bit_cast(unsigned, t);
}

__device__ __forceinline__ unsigned short f2bf(float f) {   // RNE f32->bf16
    unsigned u = __builtin_bit_cast(unsigned, f);
    u += 0x7FFF + ((u >> 16) & 1);
    return (unsigned short)(u >> 16);
}

// ---------------------------------------------------------------------------
// CSR build step 1: histogram of dst (counts pre-zeroed).
// ---------------------------------------------------------------------------
__global__ __launch_bounds__(256) void hist_kernel(
    const int* __restrict__ dst, int* __restrict__ counts)
{
    int e = blockIdx.x * 256 + threadIdx.x;
    atomicAdd(&counts[dst[e]], 1);
}

// ---------------------------------------------------------------------------
// CSR build step 2: exclusive scan -> offsets[N_NODES+1] + cursor copy.
// ---------------------------------------------------------------------------
__global__ __launch_bounds__(1024) void scan_kernel(
    const int* __restrict__ counts, int* __restrict__ offsets,
    int* __restrict__ cursor)
{
    __shared__ int part[1024];
    const int t = threadIdx.x;
    const int CH = (N_NODES + 1023) / 1024;   // 49
    const int lo = t * CH;
    const int hi = (lo + CH < N_NODES) ? lo + CH : N_NODES;
    int s = 0;
    for (int i = lo; i < hi; ++i) s += counts[i];
    part[t] = s;
    __syncthreads();
    for (int off = 1; off < 1024; off <<= 1) {
        int v = (t >= off) ? part[t - off] : 0;
        __syncthreads();
        part[t] += v;
        __syncthreads();
    }
    int run = (t > 0) ? part[t - 1] : 0;
    for (int i = lo; i < hi; ++i) {
        offsets[i] = run;
        cursor[i]  = run;
        run += counts[i];
    }
    if (t == 1023) offsets[N_NODES] = run;
}

// ---------------------------------------------------------------------------
// CSR build step 3: scatter edges into dst-sorted order; edge_attr -> f16.
// ---------------------------------------------------------------------------
__global__ __launch_bounds__(256) void scatter_kernel(
    const int* __restrict__ src, const int* __restrict__ dst,
    const float* __restrict__ edge_attr,
    int* __restrict__ cursor, int* __restrict__ sorted_src,
    uint4* __restrict__ sorted_eah)
{
    int e = blockIdx.x * 256 + threadIdx.x;
    int d = dst[e];
    int pos = atomicAdd(&cursor[d], 1);
    sorted_src[pos] = src[e];
    const float4* ea = (const float4*)(edge_attr + (size_t)e * EF);
    float4 a0 = ea[0], a1 = ea[1], a2 = ea[2], a3 = ea[3];
    uint4 o0, o1;
    o0.x = pack_h2(a0.x, a0.y); o0.y = pack_h2(a0.z, a0.w);
    o0.z = pack_h2(a1.x, a1.y); o0.w = pack_h2(a1.z, a1.w);
    o1.x = pack_h2(a2.x, a2.y); o1.y = pack_h2(a2.z, a2.w);
    o1.z = pack_h2(a3.x, a3.y); o1.w = pack_h2(a3.z, a3.w);
    sorted_eah[(size_t)pos * 2]     = o0;
    sorted_eah[(size_t)pos * 2 + 1] = o1;
}

// ---------------------------------------------------------------------------
// Graph offsets: batch is sorted; goff[g] = lower_bound(batch, g), goff[512]=N.
// ---------------------------------------------------------------------------
__global__ __launch_bounds__(512) void goff_kernel(
    const int* __restrict__ batch, int* __restrict__ goff)
{
    const int g = threadIdx.x;
    int lo = 0, hi = N_NODES;
    while (lo < hi) {
        int mid = (lo + hi) >> 1;
        if (batch[mid] < g) lo = mid + 1; else hi = mid;
    }
    goff[g] = lo;
    if (g == 0) goff[N_GRAPHS] = N_NODES;
}

// ---------------------------------------------------------------------------
// Weight prep: transpose W1/W2 (all layers) to bf16 Wt[out][k], once per call.
// ---------------------------------------------------------------------------
__global__ __launch_bounds__(256) void wprep_kernel(
    const float* __restrict__ W1, const float* __restrict__ W2,
    unsigned short* __restrict__ Wt)
{
    const int matid = blockIdx.x;          // l*2 + (0:W1, 1:W2)
    const int l = matid >> 1;
    const float* srcm = (matid & 1) ? (W2 + (size_t)l * D * D)
                                    : (W1 + (size_t)l * D * D);
    unsigned short* out = Wt + (size_t)matid * D * D;
    for (int i = 0; i < 64; ++i) {
        int idx = threadIdx.x + i * 256;
        int k = idx >> 7, n = idx & 127;
        out[n * D + k] = f2bf(srcm[idx]);
    }
}

// ---------------------------------------------------------------------------
// Per-layer aggregation (gather, no atomics):
//   zin_b[n][j] = bf16( h[n][j] + sum_e relu(h[src_e][j] + dot16(ea_e, elW[:,j]) + elb[j]) )
// ---------------------------------------------------------------------------
__global__ __launch_bounds__(128) void aggr_kernel(
    const float* __restrict__ h,
    const unsigned* __restrict__ sorted_eah,   // [E][8] half2-packed
    const int*   __restrict__ sorted_src,
    const int*   __restrict__ offsets,
    const float* __restrict__ elW,   // [16][128] this layer
    const float* __restrict__ elb,
    unsigned short* __restrict__ zin_b)
{
    const int j = threadIdx.x;
    const int n = blockIdx.x;

    half2v w2[8];
    #pragma unroll
    for (int k = 0; k < 8; ++k) {
        half2v t;
        t[0] = (_Float16)elW[(2*k    ) * D + j];
        t[1] = (_Float16)elW[(2*k + 1) * D + j];
        w2[k] = t;
    }
    const float bias = elb[j];

    const int beg = offsets[n];
    const int end = offsets[n + 1];

    __shared__ __align__(16) unsigned eas[16][8];
    __shared__ int srcs[16];
    float acc = 0.0f;

    int base = beg;
    for (; base + 16 <= end; base += 16) {
        eas[j >> 3][j & 7] = sorted_eah[(size_t)(base + (j >> 3)) * 8 + (j & 7)];
        if (j < 16) srcs[j] = sorted_src[base + j];
        __syncthreads();
        #pragma unroll
        for (int i = 0; i < 16; ++i) {
            const int s = srcs[i];
            const float hv = h[(size_t)s * D + j];
            uint4 p0 = *(const uint4*)&eas[i][0];
            uint4 p1 = *(const uint4*)&eas[i][4];
            float dot = bias;
            dot = fdot2h(__builtin_bit_cast(half2v, p0.x), w2[0], dot);
            dot = fdot2h(__builtin_bit_cast(half2v, p0.y), w2[1], dot);
            dot = fdot2h(__builtin_bit_cast(half2v, p0.z), w2[2], dot);
            dot = fdot2h(__builtin_bit_cast(half2v, p0.w), w2[3], dot);
            dot = fdot2h(__builtin_bit_cast(half2v, p1.x), w2[4], dot);
            dot = fdot2h(__builtin_bit_cast(half2v, p1.y), w2[5], dot);
            dot = fdot2h(__builtin_bit_cast(half2v, p1.z), w2[6], dot);
            dot = fdot2h(__builtin_bit_cast(half2v, p1.w), w2[7], dot);
            acc += fmaxf(hv + dot, 0.0f);
        }
        __syncthreads();
    }
    const int rem = end - base;
    if (rem > 0) {
        if ((j >> 3) < rem)
            eas[j >> 3][j & 7] = sorted_eah[(size_t)(base + (j >> 3)) * 8 + (j & 7)];
        if (j < rem) srcs[j] = sorted_src[base + j];
        __syncthreads();
        for (int i = 0; i < rem; ++i) {
            const int s = srcs[i];
            const float hv = h[(size_t)s * D + j];
            uint4 p0 = *(const uint4*)&eas[i][0];
            uint4 p1 = *(const uint4*)&eas[i][4];
            float dot = bias;
            dot = fdot2h(__builtin_bit_cast(half2v, p0.x), w2[0], dot);
            dot = fdot2h(__builtin_bit_cast(half2v, p0.y), w2[1], dot);
            dot = fdot2h(__builtin_bit_cast(half2v, p0.z), w2[2], dot);
            dot = fdot2h(__builtin_bit_cast(half2v, p0.w), w2[3], dot);
            dot = fdot2h(__builtin_bit_cast(half2v, p1.x), w2[4], dot);
            dot = fdot2h(__builtin_bit_cast(half2v, p1.y), w2[5], dot);
            dot = fdot2h(__builtin_bit_cast(half2v, p1.z), w2[6], dot);
            dot = fdot2h(__builtin_bit_cast(half2v, p1.w), w2[7], dot);
            acc += fmaxf(hv + dot, 0.0f);
        }
    }
    zin_b[(size_t)n * D + j] = f2bf(h[(size_t)n * D + j] + acc);
}

// ---------------------------------------------------------------------------
// Fused node MLP via MFMA (bf16 in, fp32 accumulate):
//   hout = relu(relu(BN(zin@W1+b1))@W2 + b2)
// 128 threads = 2 waves, 64 nodes/block. B-frags straight from global
// (Wt row gives 16 contiguous bytes per lane; 32KB, L2-resident).
// Layouts (verified m89/m120): A[m=lane&15][k=quad*8+j]; C/D row=quad*4+reg,
// col=lane&15. LDS = zmid only (17.4 KB) -> high blocks/CU.
// ---------------------------------------------------------------------------
__global__ __launch_bounds__(128) void node_mlp(
    const unsigned short* __restrict__ zin_b,   // [N][128] bf16
    const unsigned short* __restrict__ W1t,     // [128 out][128 k] bf16
    const float* __restrict__ b1,
    const float* __restrict__ bng, const float* __restrict__ bnb,
    const float* __restrict__ bnm, const float* __restrict__ bnv,
    const unsigned short* __restrict__ W2t,
    const float* __restrict__ b2,
    float* __restrict__ hout)
{
    __shared__ unsigned short zmid[64 * 136];   // 17.4 KB
    __shared__ float scale_s[128], shift_s[128], b2_s[128];

    const int tid  = threadIdx.x;
    const int wv   = tid >> 6;        // 0..1
    const int lane = tid & 63;
    const int q    = lane >> 4;
    const int m    = lane & 15;
    const int node0 = blockIdx.x * 64;

    {
        float sc = bng[tid] * rsqrtf(bnv[tid] + BN_EPS);
        scale_s[tid] = sc;
        shift_s[tid] = b1[tid] * sc + bnb[tid] - bnm[tid] * sc;  // fold b1 into BN
        b2_s[tid]    = b2[tid];
    }

    // A fragments straight from global bf16 zin
    bf16x8 a[2][4];
    #pragma unroll
    for (int sub = 0; sub < 2; ++sub) {
        int node = node0 + wv * 32 + sub * 16 + m;
        if (node >= N_NODES) node = N_NODES - 1;
        const uint4* zrow = (const uint4*)(zin_b + (size_t)node * D);
        #pragma unroll
        for (int k = 0; k < 4; ++k)
            a[sub][k] = __builtin_bit_cast(bf16x8, zrow[k * 4 + q]);
    }

    f32x4 acc[2][8];
    #pragma unroll
    for (int s2 = 0; s2 < 2; ++s2)
        #pragma unroll
        for (int t = 0; t < 8; ++t)
            acc[s2][t] = (f32x4){0.f, 0.f, 0.f, 0.f};

    __syncthreads();   // scale_s/shift_s ready (also before zmid use)

    // GEMM 1: B-frags from global W1t
    #pragma unroll
    for (int t = 0; t < 8; ++t) {
        const unsigned short* wrow = W1t + (size_t)(t * 16 + m) * D;
        bf16x8 bfr[4];
        #pragma unroll
        for (int k = 0; k < 4; ++k)
            bfr[k] = __builtin_bit_cast(bf16x8, *(const uint4*)&wrow[k * 32 + q * 8]);
        #pragma unroll
        for (int sub = 0; sub < 2; ++sub) {
            acc[sub][t] = __builtin_amdgcn_mfma_f32_16x16x32_bf16(a[sub][0], bfr[0], acc[sub][t], 0, 0, 0);
            acc[sub][t] = __builtin_amdgcn_mfma_f32_16x16x32_bf16(a[sub][1], bfr[1], acc[sub][t], 0, 0, 0);
            acc[sub][t] = __builtin_amdgcn_mfma_f32_16x16x32_bf16(a[sub][2], bfr[2], acc[sub][t], 0, 0, 0);
            acc[sub][t] = __builtin_amdgcn_mfma_f32_16x16x32_bf16(a[sub][3], bfr[3], acc[sub][t], 0, 0, 0);
        }
    }

    // epilogue 1: BN + relu -> zmid (bf16, C/D layout -> LDS)
    #pragma unroll
    for (int sub = 0; sub < 2; ++sub)
        #pragma unroll
        for (int t = 0; t < 8; ++t) {
            int col = t * 16 + m;
            float sc = scale_s[col], sh = shift_s[col];
            #pragma unroll
            for (int rr = 0; rr < 4; ++rr) {
                float v = fmaxf(acc[sub][t][rr] * sc + sh, 0.f);
                int row = wv * 32 + sub * 16 + q * 4 + rr;
                zmid[row * 136 + col] = f2bf(v);
            }
        }

    __syncthreads();   // zmid complete

    // A2 frags from zmid
    bf16x8 a2[2][4];
    #pragma unroll
    for (int sub = 0; sub < 2; ++sub) {
        const unsigned short* zr = &zmid[(wv * 32 + sub * 16 + m) * 136];
        #pragma unroll
        for (int k = 0; k < 4; ++k)
            a2[sub][k] = __builtin_bit_cast(bf16x8, *(const uint4*)&zr[k * 32 + q * 8]);
    }

    #pragma unroll
    for (int s2 = 0; s2 < 2; ++s2)
        #pragma unroll
        for (int t = 0; t < 8; ++t)
            acc[s2][t] = (f32x4){0.f, 0.f, 0.f, 0.f};

    // GEMM 2: B-frags from global W2t
    #pragma unroll
    for (int t = 0; t < 8; ++t) {
        const unsigned short* wrow = W2t + (size_t)(t * 16 + m) * D;
        bf16x8 bfr[4];
        #pragma unroll
        for (int k = 0; k < 4; ++k)
            bfr[k] = __builtin_bit_cast(bf16x8, *(const uint4*)&wrow[k * 32 + q * 8]);
        #pragma unroll
        for (int sub = 0; sub < 2; ++sub) {
            acc[sub][t] = __builtin_amdgcn_mfma_f32_16x16x32_bf16(a2[sub][0], bfr[0], acc[sub][t], 0, 0, 0);
            acc[sub][t] = __builtin_amdgcn_mfma_f32_16x16x32_bf16(a2[sub][1], bfr[1], acc[sub][t], 0, 0, 0);
            acc[sub][t] = __builtin_amdgcn_mfma_f32_16x16x32_bf16(a2[sub][2], bfr[2], acc[sub][t], 0, 0, 0);
            acc[sub][t] = __builtin_amdgcn_mfma_f32_16x16x32_bf16(a2[sub][3], bfr[3], acc[sub][t], 0, 0, 0);
        }
    }

    // epilogue 2: bias + relu -> hout (fp32). No atomics.
    #pragma unroll
    for (int sub = 0; sub < 2; ++sub)
        #pragma unroll
        for (int rr = 0; rr < 4; ++rr) {
            int node = node0 + wv * 32 + sub * 16 + q * 4 + rr;
            if (node < N_NODES) {
                float* hrow = hout + (size_t)node * D;
                #pragma unroll
                for (int t = 0; t < 8; ++t) {
                    int col = t * 16 + m;
                    hrow[col] = fmaxf(acc[sub][t][rr] + b2_s[col], 0.f);
                }
            }
        }
}

// ---------------------------------------------------------------------------
// Pool: segmented sum over sorted batch. Block g sums hout rows of graph g.
// No atomics, coalesced 512B row reads.
// ---------------------------------------------------------------------------
__global__ __launch_bounds__(128) void pool_kernel(
    const float* __restrict__ hout, const int* __restrict__ goff,
    float* __restrict__ pool, int layer_off)
{
    const int g = blockIdx.x;
    const int j = threadIdx.x;
    const int beg = goff[g], end = goff[g + 1];
    float acc = 0.0f;
    for (int r = beg; r < end; ++r)
        acc += hout[(size_t)r * D + j];
    pool[g * (LAYERS * D) + layer_off + j] = acc;
}

// ---------------------------------------------------------------------------
// Head: out[g] = relu(pool[g] @ lin1_W + lin1_b) @ lin2_W + lin2_b
// ---------------------------------------------------------------------------
__global__ __launch_bounds__(384) void head_kernel(
    const float* __restrict__ pool,
    const float* __restrict__ lin1W,
    const float* __restrict__ lin1b,
    const float* __restrict__ lin2W,
    const float* __restrict__ lin2b,
    float*       __restrict__ out)
{
    __shared__ float gs[LAYERS * D];
    __shared__ float red[LAYERS * D];
    const int g   = blockIdx.x;
    const int tid = threadIdx.x;
    gs[tid] = pool[g * (LAYERS * D) + tid];
    __syncthreads();

    float acc = lin1b[tid];
    #pragma unroll 4
    for (int k = 0; k < LAYERS * D; ++k)
        acc = fmaf(gs[k], lin1W[k * (LAYERS * D) + tid], acc);
    acc = fmaxf(acc, 0.0f);
    float p = acc * lin2W[tid];

    red[tid] = p;
    __syncthreads();
    if (tid < 128) red[tid] = red[tid] + red[tid + 128] + red[tid + 256];
    __syncthreads();
    if (tid < 64) {
        float v = red[tid] + red[tid + 64];
        v += __shfl_down(v, 32);
        v += __shfl_down(v, 16);
        v += __shfl_down(v, 8);
        v += __shfl_down(v, 4);
        v += __shfl_down(v, 2);
        v += __shfl_down(v, 1);
        if (tid == 0) out[g] = v + lin2b[0];
    }
}

// ---------------------------------------------------------------------------
extern "C" void kernel_launch(void* const* d_in, const int* in_sizes, int n_in,
                              void* d_out, int out_size, void* d_ws, size_t ws_size,
                              hipStream_t stream)
{
    const float* x         = (const float*)d_in[0];
    const float* edge_attr = (const float*)d_in[1];
    const float* elW       = (const float*)d_in[2];
    const float* elb       = (const float*)d_in[3];
    const float* W1        = (const float*)d_in[4];
    const float* b1        = (const float*)d_in[5];
    const float* bn_g      = (const float*)d_in[6];
    const float* bn_b      = (const float*)d_in[7];
    const float* bn_mean   = (const float*)d_in[8];
    const float* bn_var    = (const float*)d_in[9];
    const float* W2        = (const float*)d_in[10];
    const float* b2        = (const float*)d_in[11];
    const float* lin1W     = (const float*)d_in[12];
    const float* lin1b     = (const float*)d_in[13];
    const float* lin2W     = (const float*)d_in[14];
    const float* lin2b     = (const float*)d_in[15];
    const int*   ei        = (const int*)d_in[16];
    const int*   batch     = (const int*)d_in[17];
    const int*   src = ei;
    const int*   dst = ei + N_EDGES;

    // Workspace layout (~98 MB), all 16B-aligned:
    float*          hA         = (float*)d_ws;                              // N*128 f32
    float*          pool       = hA + (size_t)N_NODES * D;                  // G*384 f32
    unsigned short* zin_b      = (unsigned short*)(pool + (size_t)N_GRAPHS * LAYERS * D);
    unsigned short* Wt         = zin_b + (size_t)N_NODES * D;               // 6*16384 bf16
    unsigned*       sorted_eah = (unsigned*)(Wt + 6 * D * D);               // E*8 u32
    int*            sorted_src = (int*)(sorted_eah + (size_t)N_EDGES * 8);
    int*            counts     = sorted_src + N_EDGES;
    int*            offsets    = counts + N_NODES;
    int*            cursor     = offsets + N_NODES + 4;
    int*            goff       = cursor + N_NODES + 4;                      // 513 ints

    hipMemsetAsync(counts, 0, (size_t)N_NODES * sizeof(int), stream);

    // --- once-per-call prep ---
    wprep_kernel<<<6, 256, 0, stream>>>(W1, W2, Wt);
    goff_kernel<<<1, 512, 0, stream>>>(batch, goff);
    hist_kernel<<<N_EDGES / 256, 256, 0, stream>>>(dst, counts);
    scan_kernel<<<1, 1024, 0, stream>>>(counts, offsets, cursor);
    scatter_kernel<<<N_EDGES / 256, 256, 0, stream>>>(
        src, dst, edge_attr, cursor, sorted_src, (uint4*)sorted_eah);

    const float* hin = x;
    for (int l = 0; l < LAYERS; ++l) {
        aggr_kernel<<<N_NODES, 128, 0, stream>>>(
            hin, sorted_eah, sorted_src, offsets,
            elW + (size_t)l * EF * D, elb + l * D, zin_b);
        node_mlp<<<(N_NODES + 63) / 64, 128, 0, stream>>>(
            zin_b,
            Wt + (size_t)(l * 2)     * D * D, b1 + l * D,
            bn_g + l * D, bn_b + l * D, bn_mean + l * D, bn_var + l * D,
            Wt + (size_t)(l * 2 + 1) * D * D, b2 + l * D,
            hA);
        pool_kernel<<<N_GRAPHS, 128, 0, stream>>>(hA, goff, pool, l * D);
        hin = hA;
    }

    head_kernel<<<N_GRAPHS, LAYERS * D, 0, stream>>>(
        pool, lin1W, lin1b, lin2W, lin2b, (float*)d_out);
}